// Round 17
// baseline (322.687 us; speedup 1.0000x reference)
//
#include <hip/hip_runtime.h>

// GaLiTe attention layer, MI355X/gfx950 — all-fp32 (fp32 projections required:
// attn_den is a 256-term cancellation sum; bf16 decorrelates it — R2/R3).
// Shapes: T=64 B=16 DIM=512 H=8 Dh=64 ETA=4 FD=256.
// d_out = fp32 [ output(64*16*512) | kv_last(16*8*256*64) | nm_last(16*8*256) ].
//
// R17 = R14 with proj reverted to proven gemm64_core (R15/R16 variants both
// regressed — 64x64/4x4 dbuf is the local optimum at ~70us), plus:
//  1) out partial+reduce FUSED (last-block-done pattern, counters in dead p3b
//     region zeroed by scan block 0) -> 4 kernels total (~13us/gap measured).
//  2) scan5b: 16-lane groups own 1 d-col, lane owns 16 D -> butterflies
//     4 stages x 2 values (was 5x3); scan was shuffle-chain latency-bound.

#define T_N   64
#define B_N   16
#define DIM_N 512
#define H_N   8
#define DH_N  64

#define OUT_ELEMS   524288   // T*B*DIM
#define KV_ELEMS    2097152  // B*H*FD*Dh
#define PROJ_ELEMS  2719744  // 5*524288 + 3*32768

__device__ __forceinline__ float sigmoidf_(float x) {
    return 1.0f / (1.0f + __expf(-x));
}

// ---------------------------------------------------------------------------
// gemm64_core (PROVEN, untouched): 64x64 tile, BK=16, 4x4 micro, dbuf LDS.
// ---------------------------------------------------------------------------
__device__ __forceinline__ void gemm64_core(const float* __restrict__ A,
                                            const float* __restrict__ W,
                                            const float* __restrict__ bias,
                                            float* __restrict__ C, int N,
                                            int mb, int nb, int kBase, int kLen) {
    const int nbase = nb * 64;
    if (nbase >= N) return;

    __shared__ float As[2][16][68];
    __shared__ float Bs[2][16][68];

    const int tid = threadIdx.x;
    const int mbase = mb * 64;
    const int tx = tid & 15;
    const int ty = tid >> 4;
    const int sr = tid >> 2;
    const int sk = (tid & 3) << 2;
    const bool wok = (nbase + sr) < N;

    const float* Ap = A + (size_t)(mbase + sr) * 512 + kBase + sk;
    const float* Wp = W + (size_t)(nbase + sr) * 512 + kBase + sk;

    float4 av = *(const float4*)Ap;
    float4 wv = wok ? *(const float4*)Wp : make_float4(0.f, 0.f, 0.f, 0.f);
    As[0][sk + 0][sr] = av.x; As[0][sk + 1][sr] = av.y;
    As[0][sk + 2][sr] = av.z; As[0][sk + 3][sr] = av.w;
    Bs[0][sk + 0][sr] = wv.x; Bs[0][sk + 1][sr] = wv.y;
    Bs[0][sk + 2][sr] = wv.z; Bs[0][sk + 3][sr] = wv.w;

    float acc[4][4];
    #pragma unroll
    for (int i = 0; i < 4; ++i)
        #pragma unroll
        for (int j = 0; j < 4; ++j) acc[i][j] = 0.f;

    for (int k0 = 0; k0 < kLen; k0 += 16) {
        const int buf = (k0 >> 4) & 1;
        __syncthreads();
        const bool more = (k0 + 16) < kLen;
        if (more) {
            av = *(const float4*)(Ap + k0 + 16);
            wv = wok ? *(const float4*)(Wp + k0 + 16) : make_float4(0.f, 0.f, 0.f, 0.f);
        }
        #pragma unroll
        for (int k = 0; k < 16; ++k) {
            float4 a  = *(const float4*)&As[buf][k][ty << 2];
            float4 bq = *(const float4*)&Bs[buf][k][tx << 2];
            float ar[4] = {a.x, a.y, a.z, a.w};
            float br[4] = {bq.x, bq.y, bq.z, bq.w};
            #pragma unroll
            for (int i = 0; i < 4; ++i)
                #pragma unroll
                for (int j = 0; j < 4; ++j)
                    acc[i][j] = fmaf(ar[i], br[j], acc[i][j]);
        }
        if (more) {
            const int nbuf = buf ^ 1;
            As[nbuf][sk + 0][sr] = av.x; As[nbuf][sk + 1][sr] = av.y;
            As[nbuf][sk + 2][sr] = av.z; As[nbuf][sk + 3][sr] = av.w;
            Bs[nbuf][sk + 0][sr] = wv.x; Bs[nbuf][sk + 1][sr] = wv.y;
            Bs[nbuf][sk + 2][sr] = wv.z; Bs[nbuf][sk + 3][sr] = wv.w;
        }
    }

    #pragma unroll
    for (int i = 0; i < 4; ++i) {
        const int m = mbase + (ty << 2) + i;
        #pragma unroll
        for (int j = 0; j < 4; ++j) {
            const int n = nbase + (tx << 2) + j;
            if (n < N) {
                float v = acc[i][j];
                if (bias) v += bias[n];
                C[(size_t)m * N + n] = v;
            }
        }
    }
}

struct ProjW {
    const float* W[8];
    float*       D[8];
};

// proj (proven): 1D grid 1024, id = z + 8*(m + 16*n); XCD = z. Active: 688.
__global__ __launch_bounds__(256) void proj_kernel(const float* __restrict__ X, ProjW a) {
    const int id = blockIdx.x;
    const int z = id & 7;
    const int rem = id >> 3;
    const int m = rem & 15;
    const int n = rem >> 4;
    const int N = (z < 5) ? 512 : 32;
    gemm64_core(X, a.W[z], nullptr, a.D[z], N, m, n, 0, 512);
}

// ---------------------------------------------------------------------------
// out GEMM split-K=4, FUSED tail: grid 512, id = m + 16*(n + 8*kq).
// Each block writes its partial, fences, bumps done[m*8+n]; the LAST block
// (old==3) re-reads all 4 partials + bias and writes the final tile.
// Counters zeroed by scan5b block 0 (runs before this kernel, after gate).
// ---------------------------------------------------------------------------
struct OutP { float* P[4]; };
__global__ __launch_bounds__(256) void out_partial_fused_kernel(
    const float* __restrict__ A, const float* __restrict__ W,
    const float* __restrict__ bias, OutP p, int* __restrict__ done,
    float* __restrict__ out) {
    const int id = blockIdx.x;
    const int m = id & 15;
    const int n = (id >> 4) & 7;
    const int kq = id >> 7;
    gemm64_core(A, W, nullptr, p.P[kq], 512, m, n, kq * 128, 128);

    __threadfence();
    __shared__ int last;
    if (threadIdx.x == 0)
        last = (atomicAdd(&done[m * 8 + n], 1) == 3);
    __syncthreads();
    if (last) {
        __threadfence();   // acquire: partials from other XCDs visible
        // tile (m,n): 64 rows x 64 cols = 64x16 float4
        for (int idx = threadIdx.x; idx < 1024; idx += 256) {
            const int row = idx >> 4;
            const int c4  = idx & 15;
            const size_t o = (size_t)(m * 64 + row) * 512 + n * 64 + c4 * 4;
            float4 a = *(const float4*)(p.P[0] + o);
            float4 b = *(const float4*)(p.P[1] + o);
            float4 c = *(const float4*)(p.P[2] + o);
            float4 d = *(const float4*)(p.P[3] + o);
            float4 bv = *(const float4*)(bias + n * 64 + c4 * 4);
            float4 r;
            r.x = a.x + b.x + c.x + d.x + bv.x;
            r.y = a.y + b.y + c.y + d.y + bv.y;
            r.z = a.z + b.z + c.z + d.z + bv.z;
            r.w = a.w + b.w + c.w + d.w + bv.w;
            *(float4*)(out + o) = r;
        }
    }
}

// ---------------------------------------------------------------------------
// gate_kernel: precompute disc/gk/phiq per (t,b,h,D) and gv per (t,b,h,d).
// grid (8 h, 1024 rows) -> wg id % 8 = h (writer XCD = scan reader XCD).
// ---------------------------------------------------------------------------
__global__ __launch_bounds__(256) void gate_kernel(
    const float* __restrict__ qb,  const float* __restrict__ kb,
    const float* __restrict__ vb,  const float* __restrict__ bb,
    const float* __restrict__ gb,  const float* __restrict__ p1b,
    const float* __restrict__ p2b, const float* __restrict__ p3b,
    const int* __restrict__ term,
    float* __restrict__ disc_g, float* __restrict__ gk_g,
    float* __restrict__ phiq_g, float* __restrict__ gv_g) {
    const int h = blockIdx.x;
    const int row = blockIdx.y;        // t*16 + b
    const int D = threadIdx.x;
    const int e = D >> 6, di = D & 63;
    const size_t base = (size_t)row * 512 + h * 64;
    const size_t pb = (size_t)row * 32 + h * 4;

    float q = qb[base + di], k = kb[base + di], g = gb[base + di];
    float p1 = p1b[pb + e], p2 = p2b[pb + e], p3 = p3b[pb + e];
    float mask = 1.0f - (float)term[row];
    float gf = sigmoidf_(p3) * sigmoidf_(g);

    const size_t o = ((size_t)row * 8 + h) * 256 + D;
    disc_g[o] = (1.0f - gf) * mask;
    gk_g[o]   = fmaxf(p1, 0.f) * k * gf;
    phiq_g[o] = fmaxf(p2, 0.f) * q;
    if (D < 64)
        gv_g[((size_t)row * 8 + h) * 64 + D] = vb[base + D] * sigmoidf_(bb[base + D]);
}

// ---------------------------------------------------------------------------
// scan5b: d-split x4. Grid 512: blk = s*128 + bh (XCD = bh%8 = h).
// Block 256 thr = 4 waves; wave = 4 INDEPENDENT 16-lane groups.
// Group g16 = l>>4 owns ONE d-col: dcol = s*16 + w*4 + g16.
// Lane li = l&15 owns D = 16*li .. +16 (group spans all 256 D).
// State/lane: kv[16] (one col), nm[16]. Butterflies: 4 stages xor(1..8)
// x 2 values (n0, den) — stay within the 16-lane group.
// Block 0 additionally zeroes the out-GEMM done counters (dead p3b region).
// ---------------------------------------------------------------------------
__global__ __launch_bounds__(256) void scan5b_kernel(
    const float* __restrict__ disc_g, const float* __restrict__ gk_g,
    const float* __restrict__ phiq_g, const float* __restrict__ gv_g,
    float* __restrict__ vb /* attn out */,
    const float* __restrict__ kv0, const float* __restrict__ nm0,
    float* __restrict__ dout, int* __restrict__ done) {
    const int blk = blockIdx.x;       // 512 = 4 splits x 128 bh
    if (blk == 0 && threadIdx.x < 128) done[threadIdx.x] = 0;
    const int bh = blk & 127;
    const int s  = blk >> 7;          // 0..3
    const int b  = bh >> 3;
    const int h  = bh & 7;
    const int tid = threadIdx.x;
    const int w = tid >> 6;
    const int l = tid & 63;
    const int g16 = l >> 4;
    const int li  = l & 15;
    const int dcol = s * 16 + w * 4 + g16;   // group's d-col
    const int D0 = li << 4;                  // lane's 16 D

    float kv[16];
    float nm[16];
    {
        const float* kp = kv0 + ((size_t)bh * 256 + D0) * 64 + dcol;
        #pragma unroll
        for (int j = 0; j < 16; ++j) kv[j] = kp[(size_t)j * 64];
        const float* np = nm0 + (size_t)bh * 256 + D0;
        #pragma unroll
        for (int j = 0; j < 16; j += 4) {
            float4 r = *(const float4*)(np + j);
            nm[j] = r.x; nm[j + 1] = r.y; nm[j + 2] = r.z; nm[j + 3] = r.w;
        }
    }

    // preload t=0
    float4 cd[4], cg[4], cp[4]; float cgv;
    {
        const size_t go = ((size_t)b * 8 + h) * 256 + D0;
        #pragma unroll
        for (int j = 0; j < 4; ++j) {
            cd[j] = *(const float4*)(disc_g + go + j * 4);
            cg[j] = *(const float4*)(gk_g   + go + j * 4);
            cp[j] = *(const float4*)(phiq_g + go + j * 4);
        }
        cgv = gv_g[((size_t)b * 8 + h) * 64 + dcol];
    }

    for (int t = 0; t < T_N; ++t) {
        const int row = t * B_N + b;
        const size_t base = (size_t)row * 512 + h * 64;

        // prefetch t+1
        float4 nd[4] = {}, ng[4] = {}, np4[4] = {}; float ngv = 0.f;
        if (t + 1 < T_N) {
            const size_t go2 = ((size_t)(row + B_N) * 8 + h) * 256 + D0;
            #pragma unroll
            for (int j = 0; j < 4; ++j) {
                nd[j]  = *(const float4*)(disc_g + go2 + j * 4);
                ng[j]  = *(const float4*)(gk_g   + go2 + j * 4);
                np4[j] = *(const float4*)(phiq_g + go2 + j * 4);
            }
            ngv = gv_g[((size_t)(row + B_N) * 8 + h) * 64 + dcol];
        }

        float den = 0.f, n0 = 0.f;
        #pragma unroll
        for (int q4 = 0; q4 < 4; ++q4) {
            const float dj[4]  = {cd[q4].x, cd[q4].y, cd[q4].z, cd[q4].w};
            const float gkj[4] = {cg[q4].x, cg[q4].y, cg[q4].z, cg[q4].w};
            const float phj[4] = {cp[q4].x, cp[q4].y, cp[q4].z, cp[q4].w};
            #pragma unroll
            for (int j = 0; j < 4; ++j) {
                const int jj = q4 * 4 + j;
                nm[jj] = dj[j] * nm[jj] + gkj[j];
                den = fmaf(phj[j], nm[jj], den);
                kv[jj] = dj[j] * kv[jj] + gkj[j] * cgv;
                n0 = fmaf(phj[j], kv[jj], n0);
            }
        }

        // 4-stage butterflies within the 16-lane group (xor <= 8)
        #pragma unroll
        for (int ofs = 1; ofs <= 8; ofs <<= 1) {
            n0  += __shfl_xor(n0, ofs);
            den += __shfl_xor(den, ofs);
        }

        if (li == 0) vb[base + dcol] = n0 / (den + 1e-6f);

        #pragma unroll
        for (int j = 0; j < 4; ++j) { cd[j] = nd[j]; cg[j] = ng[j]; cp[j] = np4[j]; }
        cgv = ngv;
    }

    // final states
    {
        float* kp = dout + OUT_ELEMS + ((size_t)bh * 256 + D0) * 64 + dcol;
        #pragma unroll
        for (int j = 0; j < 16; ++j) kp[(size_t)j * 64] = kv[j];
        if (s == 0 && w == 0 && g16 == 0) {
            float* np = dout + OUT_ELEMS + KV_ELEMS + (size_t)bh * 256 + D0;
            #pragma unroll
            for (int j = 0; j < 16; j += 4)
                *(float4*)(np + j) = make_float4(nm[j], nm[j + 1], nm[j + 2], nm[j + 3]);
        }
    }
}

// ---------------------------------------------------------------------------
extern "C" void kernel_launch(void* const* d_in, const int* in_sizes, int n_in,
                              void* d_out, int out_size, void* d_ws, size_t ws_size,
                              hipStream_t stream) {
    (void)in_sizes; (void)n_in; (void)out_size; (void)ws_size;

    const float* X    = (const float*)d_in[0];
    const int*   term = (const int*)  d_in[1];
    const float* kv0  = (const float*)d_in[2];
    const float* nm0  = (const float*)d_in[3];
    const float* Wo   = (const float*)d_in[12];
    const float* bo   = (const float*)d_in[13];

    float* out = (float*)d_out;

    // ---- workspace (38.1 MB total — PROVEN available since R9) ----
    float* qb  = (float*)d_ws;            // proj outputs; qb/kb/bb/gb reused
    float* kb  = qb  + 524288;            // as out-GEMM partials after gate
    float* vb  = kb  + 524288;            // v, later attn
    float* bb  = vb  + 524288;
    float* gb  = bb  + 524288;
    float* p1b = gb  + 524288;
    float* p2b = p1b + 32768;
    float* p3b = p2b + 32768;             // dead after gate -> done counters
    float* disc_g = p3b + 32768;          // 26 MB gating region
    float* gk_g   = disc_g + 2097152;
    float* phiq_g = gk_g   + 2097152;
    float* gv_g   = phiq_g + 2097152;
    int*   done   = (int*)p3b;            // 128 counters, zeroed by scan blk 0

    ProjW pa;
    pa.W[0] = (const float*)d_in[4];  pa.W[1] = (const float*)d_in[5];
    pa.W[2] = (const float*)d_in[6];  pa.W[3] = (const float*)d_in[7];
    pa.W[4] = (const float*)d_in[8];  pa.W[5] = (const float*)d_in[9];
    pa.W[6] = (const float*)d_in[10]; pa.W[7] = (const float*)d_in[11];
    pa.D[0] = qb;  pa.D[1] = kb;  pa.D[2] = vb;  pa.D[3] = bb;
    pa.D[4] = gb;  pa.D[5] = p1b; pa.D[6] = p2b; pa.D[7] = p3b;
    proj_kernel<<<1024, 256, 0, stream>>>(X, pa);

    gate_kernel<<<dim3(8, 1024), 256, 0, stream>>>(qb, kb, vb, bb, gb,
                                                   p1b, p2b, p3b, term,
                                                   disc_g, gk_g, phiq_g, gv_g);

    scan5b_kernel<<<512, 256, 0, stream>>>(disc_g, gk_g, phiq_g, gv_g,
                                           vb, kv0, nm0, out, done);

    OutP op; op.P[0] = qb; op.P[1] = kb; op.P[2] = bb; op.P[3] = gb;
    out_partial_fused_kernel<<<512, 256, 0, stream>>>(vb, Wo, bo, op, done, out);
}

// Round 18
// 223.547 us; speedup vs baseline: 1.4435x; 1.4435x over previous
//
#include <hip/hip_runtime.h>

// GaLiTe attention layer, MI355X/gfx950 — all-fp32 (fp32 projections required:
// attn_den is a 256-term cancellation sum; bf16 decorrelates it — R2/R3).
// Shapes: T=64 B=16 DIM=512 H=8 Dh=64 ETA=4 FD=256.
// d_out = fp32 [ output(64*16*512) | kv_last(16*8*256*64) | nm_last(16*8*256) ].
//
// R18 = exact revert to R14 (best measured: 223.7 us). Component provenance:
//  - proj gemm64_core, 688 blocks, XCD=z swizzle: 70 us. Alternatives all
//    regressed: split-K (R13, DS-bound not k-bound), 128^2 tile (R15, 0.72
//    blocks/CU latency-exposed), register-A (R16, vmcnt on critical path).
//  - gate precompute: ~10 us (took inline transcendentals off the scan chain).
//  - scan5 (4 d-splits, 32-lane halves, 5x3 butterflies): ~61 us. Best of 5
//    scan layouts (R7 100 / scan4x8 70 / scan16 103 / scan5 61 / scan5b 103).
//  - out split-K=4 partials (dead-buffer aliased) + separate reduce: 15+3 us
//    vs 84 monolithic. R17's fused last-block tail cost ~100 us: per-block
//    device __threadfence (L2 drain) x512 >> one end-of-kernel flush + gap.

#define T_N   64
#define B_N   16
#define DIM_N 512
#define H_N   8
#define DH_N  64

#define OUT_ELEMS   524288   // T*B*DIM
#define KV_ELEMS    2097152  // B*H*FD*Dh
#define PROJ_ELEMS  2719744  // 5*524288 + 3*32768

__device__ __forceinline__ float sigmoidf_(float x) {
    return 1.0f / (1.0f + __expf(-x));
}

// ---------------------------------------------------------------------------
// gemm64_core (PROVEN): 64x64 tile, BK=16, 4x4 micro, double-buffered LDS
// (1 barrier/tile), LDS stride 68. ~77% of its structural DS-throughput bound.
// ---------------------------------------------------------------------------
__device__ __forceinline__ void gemm64_core(const float* __restrict__ A,
                                            const float* __restrict__ W,
                                            const float* __restrict__ bias,
                                            float* __restrict__ C, int N,
                                            int mb, int nb, int kBase, int kLen) {
    const int nbase = nb * 64;
    if (nbase >= N) return;

    __shared__ float As[2][16][68];
    __shared__ float Bs[2][16][68];

    const int tid = threadIdx.x;
    const int mbase = mb * 64;
    const int tx = tid & 15;
    const int ty = tid >> 4;
    const int sr = tid >> 2;
    const int sk = (tid & 3) << 2;
    const bool wok = (nbase + sr) < N;

    const float* Ap = A + (size_t)(mbase + sr) * 512 + kBase + sk;
    const float* Wp = W + (size_t)(nbase + sr) * 512 + kBase + sk;

    float4 av = *(const float4*)Ap;
    float4 wv = wok ? *(const float4*)Wp : make_float4(0.f, 0.f, 0.f, 0.f);
    As[0][sk + 0][sr] = av.x; As[0][sk + 1][sr] = av.y;
    As[0][sk + 2][sr] = av.z; As[0][sk + 3][sr] = av.w;
    Bs[0][sk + 0][sr] = wv.x; Bs[0][sk + 1][sr] = wv.y;
    Bs[0][sk + 2][sr] = wv.z; Bs[0][sk + 3][sr] = wv.w;

    float acc[4][4];
    #pragma unroll
    for (int i = 0; i < 4; ++i)
        #pragma unroll
        for (int j = 0; j < 4; ++j) acc[i][j] = 0.f;

    for (int k0 = 0; k0 < kLen; k0 += 16) {
        const int buf = (k0 >> 4) & 1;
        __syncthreads();
        const bool more = (k0 + 16) < kLen;
        if (more) {
            av = *(const float4*)(Ap + k0 + 16);
            wv = wok ? *(const float4*)(Wp + k0 + 16) : make_float4(0.f, 0.f, 0.f, 0.f);
        }
        #pragma unroll
        for (int k = 0; k < 16; ++k) {
            float4 a  = *(const float4*)&As[buf][k][ty << 2];
            float4 bq = *(const float4*)&Bs[buf][k][tx << 2];
            float ar[4] = {a.x, a.y, a.z, a.w};
            float br[4] = {bq.x, bq.y, bq.z, bq.w};
            #pragma unroll
            for (int i = 0; i < 4; ++i)
                #pragma unroll
                for (int j = 0; j < 4; ++j)
                    acc[i][j] = fmaf(ar[i], br[j], acc[i][j]);
        }
        if (more) {
            const int nbuf = buf ^ 1;
            As[nbuf][sk + 0][sr] = av.x; As[nbuf][sk + 1][sr] = av.y;
            As[nbuf][sk + 2][sr] = av.z; As[nbuf][sk + 3][sr] = av.w;
            Bs[nbuf][sk + 0][sr] = wv.x; Bs[nbuf][sk + 1][sr] = wv.y;
            Bs[nbuf][sk + 2][sr] = wv.z; Bs[nbuf][sk + 3][sr] = wv.w;
        }
    }

    #pragma unroll
    for (int i = 0; i < 4; ++i) {
        const int m = mbase + (ty << 2) + i;
        #pragma unroll
        for (int j = 0; j < 4; ++j) {
            const int n = nbase + (tx << 2) + j;
            if (n < N) {
                float v = acc[i][j];
                if (bias) v += bias[n];
                C[(size_t)m * N + n] = v;
            }
        }
    }
}

struct ProjW {
    const float* W[8];
    float*       D[8];
};

// proj (proven): 1D grid 1024, id = z + 8*(m + 16*n); XCD = z. Active: 688.
__global__ __launch_bounds__(256) void proj_kernel(const float* __restrict__ X, ProjW a) {
    const int id = blockIdx.x;
    const int z = id & 7;
    const int rem = id >> 3;
    const int m = rem & 15;
    const int n = rem >> 4;
    const int N = (z < 5) ? 512 : 32;
    gemm64_core(X, a.W[z], nullptr, a.D[z], N, m, n, 0, 512);
}

// Fallback out GEMM (full K) — tiny-ws path only.
__global__ __launch_bounds__(256) void out_gemm_kernel(const float* __restrict__ A,
                                                       const float* __restrict__ W,
                                                       const float* __restrict__ bias,
                                                       float* __restrict__ C) {
    gemm64_core(A, W, bias, C, 512, blockIdx.x, blockIdx.y, 0, 512);
}

// out GEMM split-K=4 partials: grid 512, id = m + 16*(n + 8*kq); XCD = m%8.
struct OutP { float* P[4]; };
__global__ __launch_bounds__(256) void out_partial_kernel(const float* __restrict__ A,
                                                          const float* __restrict__ W,
                                                          OutP p) {
    const int id = blockIdx.x;
    const int m = id & 15;
    const int n = (id >> 4) & 7;
    const int kq = id >> 7;
    gemm64_core(A, W, nullptr, p.P[kq], 512, m, n, kq * 128, 128);
}

// reduce: out = P0+P1+P2+P3 + bias (fixed order -> deterministic). 131072 f4.
__global__ __launch_bounds__(256) void out_reduce_kernel(
    const float* __restrict__ p0, const float* __restrict__ p1,
    const float* __restrict__ p2, const float* __restrict__ p3,
    const float* __restrict__ bias, float* __restrict__ out) {
    const int i = blockIdx.x * 256 + threadIdx.x;     // float4 index
    float4 a = ((const float4*)p0)[i];
    float4 b = ((const float4*)p1)[i];
    float4 c = ((const float4*)p2)[i];
    float4 d = ((const float4*)p3)[i];
    float4 bv = ((const float4*)bias)[i & 127];
    float4 r;
    r.x = a.x + b.x + c.x + d.x + bv.x;
    r.y = a.y + b.y + c.y + d.y + bv.y;
    r.z = a.z + b.z + c.z + d.z + bv.z;
    r.w = a.w + b.w + c.w + d.w + bv.w;
    ((float4*)out)[i] = r;
}

// ---------------------------------------------------------------------------
// gate_kernel: precompute disc/gk/phiq per (t,b,h,D) and gv per (t,b,h,d).
// grid (8 h, 1024 rows) -> wg id % 8 = h (writer XCD = scan reader XCD).
// ---------------------------------------------------------------------------
__global__ __launch_bounds__(256) void gate_kernel(
    const float* __restrict__ qb,  const float* __restrict__ kb,
    const float* __restrict__ vb,  const float* __restrict__ bb,
    const float* __restrict__ gb,  const float* __restrict__ p1b,
    const float* __restrict__ p2b, const float* __restrict__ p3b,
    const int* __restrict__ term,
    float* __restrict__ disc_g, float* __restrict__ gk_g,
    float* __restrict__ phiq_g, float* __restrict__ gv_g) {
    const int h = blockIdx.x;
    const int row = blockIdx.y;        // t*16 + b
    const int D = threadIdx.x;
    const int e = D >> 6, di = D & 63;
    const size_t base = (size_t)row * 512 + h * 64;
    const size_t pb = (size_t)row * 32 + h * 4;

    float q = qb[base + di], k = kb[base + di], g = gb[base + di];
    float p1 = p1b[pb + e], p2 = p2b[pb + e], p3 = p3b[pb + e];
    float mask = 1.0f - (float)term[row];
    float gf = sigmoidf_(p3) * sigmoidf_(g);

    const size_t o = ((size_t)row * 8 + h) * 256 + D;
    disc_g[o] = (1.0f - gf) * mask;
    gk_g[o]   = fmaxf(p1, 0.f) * k * gf;
    phiq_g[o] = fmaxf(p2, 0.f) * q;
    if (D < 64)
        gv_g[((size_t)row * 8 + h) * 64 + D] = vb[base + D] * sigmoidf_(bb[base + D]);
}

// ---------------------------------------------------------------------------
// scan5 (PROVEN best): d-split x4. Grid 512: blk = s*128 + bh (XCD = bh%8 = h).
// Block 256 thr = 4 waves; wave = 2 INDEPENDENT 32-lane halves.
// Wave w covers 4 d-cols; half (l>>5) owns cols s*16+w*4+2*half+{0,1}.
// Lane li = l&31 owns D = 8*li..8*li+8 (each half spans all 256 D).
// Butterflies: 5 stages xor(1..16) x 3 values (stay within the half).
// attn overwrites vb (scan never reads vb; out_partial reads it after).
// ---------------------------------------------------------------------------
__global__ __launch_bounds__(256) void scan5_kernel(
    const float* __restrict__ disc_g, const float* __restrict__ gk_g,
    const float* __restrict__ phiq_g, const float* __restrict__ gv_g,
    float* __restrict__ vb /* attn out */,
    const float* __restrict__ kv0, const float* __restrict__ nm0,
    float* __restrict__ dout) {
    const int blk = blockIdx.x;       // 512 = 4 splits x 128 bh
    const int bh = blk & 127;
    const int s  = blk >> 7;          // 0..3
    const int b  = bh >> 3;
    const int h  = bh & 7;
    const int tid = threadIdx.x;
    const int w = tid >> 6;
    const int l = tid & 63;
    const int half = l >> 5;
    const int li = l & 31;
    const int d0 = s * 16 + w * 4 + half * 2;   // lane's 2 d-cols
    const int D0 = li << 3;                     // lane's 8 D

    float kv[8][2];
    float nm[8];
    {
        const float* kp = kv0 + ((size_t)bh * 256 + D0) * 64 + d0;
        #pragma unroll
        for (int j = 0; j < 8; ++j) {
            float2 r = *(const float2*)(kp + (size_t)j * 64);
            kv[j][0] = r.x; kv[j][1] = r.y;
        }
        float4 na = *(const float4*)(nm0 + (size_t)bh * 256 + D0);
        float4 nb_ = *(const float4*)(nm0 + (size_t)bh * 256 + D0 + 4);
        nm[0] = na.x; nm[1] = na.y; nm[2] = na.z; nm[3] = na.w;
        nm[4] = nb_.x; nm[5] = nb_.y; nm[6] = nb_.z; nm[7] = nb_.w;
    }

    float4 cd0, cd1, cg0, cg1, cp0, cp1; float2 cgv;
    {
        const size_t go = ((size_t)b * 8 + h) * 256 + D0;
        cd0 = *(const float4*)(disc_g + go);  cd1 = *(const float4*)(disc_g + go + 4);
        cg0 = *(const float4*)(gk_g + go);    cg1 = *(const float4*)(gk_g + go + 4);
        cp0 = *(const float4*)(phiq_g + go);  cp1 = *(const float4*)(phiq_g + go + 4);
        cgv = *(const float2*)(gv_g + ((size_t)b * 8 + h) * 64 + d0);
    }

    for (int t = 0; t < T_N; ++t) {
        const int row = t * B_N + b;
        const size_t base = (size_t)row * 512 + h * 64;

        float4 nd0 = {}, nd1 = {}, ng0 = {}, ng1 = {}, np0 = {}, np1 = {};
        float2 ngv = {};
        if (t + 1 < T_N) {
            const size_t go2 = ((size_t)(row + B_N) * 8 + h) * 256 + D0;
            nd0 = *(const float4*)(disc_g + go2); nd1 = *(const float4*)(disc_g + go2 + 4);
            ng0 = *(const float4*)(gk_g + go2);   ng1 = *(const float4*)(gk_g + go2 + 4);
            np0 = *(const float4*)(phiq_g + go2); np1 = *(const float4*)(phiq_g + go2 + 4);
            ngv = *(const float2*)(gv_g + ((size_t)(row + B_N) * 8 + h) * 64 + d0);
        }

        const float dj[8]  = {cd0.x, cd0.y, cd0.z, cd0.w, cd1.x, cd1.y, cd1.z, cd1.w};
        const float gkj[8] = {cg0.x, cg0.y, cg0.z, cg0.w, cg1.x, cg1.y, cg1.z, cg1.w};
        const float phj[8] = {cp0.x, cp0.y, cp0.z, cp0.w, cp1.x, cp1.y, cp1.z, cp1.w};

        float den = 0.f, n0 = 0.f, n1 = 0.f;
        #pragma unroll
        for (int j = 0; j < 8; ++j) {
            nm[j] = dj[j] * nm[j] + gkj[j];
            den = fmaf(phj[j], nm[j], den);
            kv[j][0] = dj[j] * kv[j][0] + gkj[j] * cgv.x; n0 = fmaf(phj[j], kv[j][0], n0);
            kv[j][1] = dj[j] * kv[j][1] + gkj[j] * cgv.y; n1 = fmaf(phj[j], kv[j][1], n1);
        }

        #pragma unroll
        for (int ofs = 1; ofs <= 16; ofs <<= 1) {
            n0  += __shfl_xor(n0, ofs);
            n1  += __shfl_xor(n1, ofs);
            den += __shfl_xor(den, ofs);
        }

        if (li == 0) {
            vb[base + d0]     = n0 / (den + 1e-6f);
            vb[base + d0 + 1] = n1 / (den + 1e-6f);
        }

        cd0 = nd0; cd1 = nd1; cg0 = ng0; cg1 = ng1; cp0 = np0; cp1 = np1; cgv = ngv;
    }

    {
        float* kp = dout + OUT_ELEMS + ((size_t)bh * 256 + D0) * 64 + d0;
        #pragma unroll
        for (int j = 0; j < 8; ++j)
            *(float2*)(kp + (size_t)j * 64) = make_float2(kv[j][0], kv[j][1]);
        if (s == 0 && w == 0 && half == 0) {
            float* np = dout + OUT_ELEMS + KV_ELEMS + (size_t)bh * 256 + D0;
            *(float4*)np       = make_float4(nm[0], nm[1], nm[2], nm[3]);
            *(float4*)(np + 4) = make_float4(nm[4], nm[5], nm[6], nm[7]);
        }
    }
}

// ---------------------------------------------------------------------------
extern "C" void kernel_launch(void* const* d_in, const int* in_sizes, int n_in,
                              void* d_out, int out_size, void* d_ws, size_t ws_size,
                              hipStream_t stream) {
    (void)in_sizes; (void)n_in; (void)out_size;

    const float* X    = (const float*)d_in[0];
    const int*   term = (const int*)  d_in[1];
    const float* kv0  = (const float*)d_in[2];
    const float* nm0  = (const float*)d_in[3];
    const float* Wo   = (const float*)d_in[12];
    const float* bo   = (const float*)d_in[13];

    float* out = (float*)d_out;

    // ---- workspace (38.1 MB total — PROVEN available since R9) ----
    float* qb  = (float*)d_ws;            // proj outputs; qb/kb/bb/gb reused
    float* kb  = qb  + 524288;            // as out-GEMM partials after gate
    float* vb  = kb  + 524288;            // v, later attn
    float* bb  = vb  + 524288;
    float* gb  = bb  + 524288;
    float* p1b = gb  + 524288;
    float* p2b = p1b + 32768;
    float* p3b = p2b + 32768;
    float* disc_g = p3b + 32768;          // 26 MB gating region
    float* gk_g   = disc_g + 2097152;
    float* phiq_g = gk_g   + 2097152;
    float* gv_g   = phiq_g + 2097152;
    const size_t need_bytes = (size_t)(PROJ_ELEMS + 6815744) * 4;  // 38.1 MB
    const bool big = ws_size >= need_bytes;

    ProjW pa;
    pa.W[0] = (const float*)d_in[4];  pa.W[1] = (const float*)d_in[5];
    pa.W[2] = (const float*)d_in[6];  pa.W[3] = (const float*)d_in[7];
    pa.W[4] = (const float*)d_in[8];  pa.W[5] = (const float*)d_in[9];
    pa.W[6] = (const float*)d_in[10]; pa.W[7] = (const float*)d_in[11];
    pa.D[0] = qb;  pa.D[1] = kb;  pa.D[2] = vb;  pa.D[3] = bb;
    pa.D[4] = gb;  pa.D[5] = p1b; pa.D[6] = p2b; pa.D[7] = p3b;
    proj_kernel<<<1024, 256, 0, stream>>>(X, pa);

    gate_kernel<<<dim3(8, 1024), 256, 0, stream>>>(qb, kb, vb, bb, gb,
                                                   p1b, p2b, p3b, term,
                                                   disc_g, gk_g, phiq_g, gv_g);
    scan5_kernel<<<512, 256, 0, stream>>>(disc_g, gk_g, phiq_g, gv_g,
                                          vb, kv0, nm0, out);
    if (big) {
        // out = attn @ Wo^T + bo, split-K=4 into the dead q/k/b/g buffers
        OutP op; op.P[0] = qb; op.P[1] = kb; op.P[2] = bb; op.P[3] = gb;
        out_partial_kernel<<<512, 256, 0, stream>>>(vb, Wo, op);
        out_reduce_kernel<<<512, 256, 0, stream>>>(qb, kb, bb, gb, bo, out);
    } else {
        out_gemm_kernel<<<dim3(16, 8), 256, 0, stream>>>(vb, Wo, bo, out);
    }
}